// Round 10
// baseline (97.297 us; speedup 1.0000x reference)
//
#include <hip/hip_runtime.h>

#define S_DIM 128
#define A_DIM 96
#define B_DIM 256
#define LX 512
#define LY 256

// Dynamic-LDS layout (byte offsets from base):
//   [0, 132096)        packed cost quads: 129 rows x 64 lanes x 16B (row 128 = +inf)
//   [132096, 136704)   sX: 1152 ints = packed-row byte offsets (256 left pad -> inf row,
//                      512 xs entries, right pad -> row 0)
#define PK_ROWB   1024u
#define INF_ROW   128
#define SX_OFF    132096u
#define LDS_BYTES 136704

typedef float f32x4 __attribute__((ext_vector_type(4)));
typedef int   i32x4 __attribute__((ext_vector_type(4)));

template <int CTRL>
__device__ __forceinline__ float dpp_mov(float oldv, float src) {
    return __int_as_float(__builtin_amdgcn_update_dpp(
        __float_as_int(oldv), __float_as_int(src), CTRL, 0xF, 0xF, false));
}
#define DPP_SHR1(o, s) dpp_mov<0x138>((o), (s))   // lane l <- lane l-1 ; lane0 <- o

__device__ __forceinline__ f32x4 ds_load4(uint32_t addr) {
    f32x4 v;
    asm volatile("ds_read_b128 %0, %1" : "=v"(v) : "v"(addr));
    return v;
}
__device__ __forceinline__ i32x4 ds_load4i(uint32_t addr) {
    i32x4 v;
    asm volatile("ds_read_b128 %0, %1" : "=v"(v) : "v"(addr));
    return v;
}
// Counted wait fenced on both sides (rule #18): nothing crosses the waitcnt.
#define WAITK(N) do { __builtin_amdgcn_sched_barrier(0);                      \
                      asm volatile("s_waitcnt lgkmcnt(" #N ")" ::: "memory"); \
                      __builtin_amdgcn_sched_barrier(0); } while (0)

// Table[x][y] = cost - 2 = -1 - softmax(P,axis=1)[x][y]  (g-domain costs)
__global__ __launch_bounds__(64) void softmax_kernel(const float* __restrict__ P,
                                                     float* __restrict__ C) {
    int row = blockIdx.x, lane = threadIdx.x;
    const float* p = P + row * A_DIM;
    float v0 = p[lane];
    float v1 = (lane < A_DIM - 64) ? p[64 + lane] : -1e30f;
    float m = fmaxf(v0, v1);
    #pragma unroll
    for (int d = 32; d > 0; d >>= 1) m = fmaxf(m, __shfl_xor(m, d));
    float e0 = expf(v0 - m);
    float e1 = (lane < A_DIM - 64) ? expf(v1 - m) : 0.0f;
    float s = e0 + e1;
    #pragma unroll
    for (int d = 32; d > 0; d >>= 1) s += __shfl_xor(s, d);
    float inv = 1.0f / s;
    C[row * A_DIM + lane] = -1.0f - e0 * inv;
    if (lane < A_DIM - 64) C[row * A_DIM + 64 + lane] = -1.0f - e1 * inv;
}

// One DP row in g-domain (g = D - i - j):
//   g[i][j] = min(g[i][j-1], g[i-1][j], g[i-1][j-1] + (c-2))
// SSd = left-neighbor g3 after row i-1 (diag), SSl = after row i (left).
// fminf(fminf(..)..) pairs fold to v_min3_f32.
#define ROWSTEP(SSd, SSl, Q)                              \
    {                                                     \
        float a0 = (SSd) + (Q).x;                         \
        float n0 = fminf(fminf((SSl), g0), a0);           \
        float a1 = g0 + (Q).y;                            \
        float n1 = fminf(fminf(n0, g1), a1);              \
        float a2 = g1 + (Q).z;                            \
        float n2 = fminf(fminf(n1, g2), a2);              \
        float a3 = g2 + (Q).w;                            \
        float n3 = fminf(fminf(n2, g3), a3);              \
        g0 = n0; g1 = n1; g2 = n2; g3 = n3;               \
    }

// Phase t: issue next-phase DS (4 cost quads via xg##P = x's of phase t+1,
// loaded 2 phases ago; reload xg##P with x's of phase t+3), compute boundary
// DPPs from prev-phase registers UNDER the drain, then wait + 4 rows.
#define PHASE_FULL(P, Q)                                          \
    {                                                             \
        q##Q##0 = ds_load4((uint32_t)xg##P.x + lane16b);          \
        q##Q##1 = ds_load4((uint32_t)xg##P.y + lane16b);          \
        q##Q##2 = ds_load4((uint32_t)xg##P.z + lane16b);          \
        q##Q##3 = ds_load4((uint32_t)xg##P.w + lane16b);          \
        xg##P = ds_load4i(xaddr); xaddr += 16u;                   \
        float ss0 = DPP_SHR1(0.f, h0);                            \
        float ss1 = DPP_SHR1(0.f, h1);                            \
        float ss2 = DPP_SHR1(0.f, h2);                            \
        float ss3 = DPP_SHR1(0.f, h3);                            \
        float ss4 = DPP_SHR1(0.f, g3);                            \
        WAITK(5);                                                 \
        h0 = g3;                                                  \
        ROWSTEP(ss0, ss1, q##P##0); h1 = g3;                      \
        ROWSTEP(ss1, ss2, q##P##1); h2 = g3;                      \
        ROWSTEP(ss2, ss3, q##P##2); h3 = g3;                      \
        ROWSTEP(ss3, ss4, q##P##3);                               \
    }

#define TAIL(P)                                                   \
    {                                                             \
        float ss0 = DPP_SHR1(0.f, h0);                            \
        float ss1 = DPP_SHR1(0.f, h1);                            \
        float ss2 = DPP_SHR1(0.f, h2);                            \
        float ss3 = DPP_SHR1(0.f, h3);                            \
        float ss4 = DPP_SHR1(0.f, g3);                            \
        WAITK(0);                                                 \
        ROWSTEP(ss0, ss1, q##P##0);                               \
        if (r_star > 0) { ROWSTEP(ss1, ss2, q##P##1);             \
          if (r_star > 1) { ROWSTEP(ss2, ss3, q##P##2);           \
            if (r_star > 2) { ROWSTEP(ss3, ss4, q##P##3); } } }   \
    }

__global__ __launch_bounds__(64) void dp_kernel(const float* __restrict__ C,
                                                const int* __restrict__ xs,
                                                const int* __restrict__ ys,
                                                const int* __restrict__ xlen,
                                                const int* __restrict__ ylen,
                                                float* __restrict__ out) {
    extern __shared__ char smem[];
    const int b = blockIdx.x, lane = threadIdx.x;
    const uint32_t base32 = (uint32_t)(uintptr_t)smem;

    const int4 yv = *(const int4*)(ys + b * LY + lane * 4);
    const int y0 = yv.x, y1 = yv.y, y2 = yv.z, y3 = yv.w;

    // ---- sX: packed-row byte offsets, with inf-row left pad / row-0 right pad ----
    {
        int* sx = (int*)(smem + SX_OFF);
        const int* xsb = xs + b * LX;
        #pragma unroll
        for (int k = 0; k < 4; ++k) sx[lane + 64 * k] = INF_ROW << 10;      // left pad
        #pragma unroll
        for (int k = 0; k < 8; ++k) sx[256 + lane + 64 * k] = xsb[lane + 64 * k] << 10;
        #pragma unroll
        for (int k = 0; k < 6; ++k) sx[768 + lane + 64 * k] = 0;            // right pad
    }

    // ---- build per-lane packed quads straight from global (L2-hot, pipelined):
    //      packed[x][lane] = {C[x][y0..y3]} ----
    {
        char* pk = smem;
        const uint32_t woff = (uint32_t)(lane << 4);
        #pragma unroll 2
        for (int x = 0; x < S_DIM; x += 2) {
            const float* r0 = C + A_DIM * x;
            const float* r1 = r0 + A_DIM;
            f32x4 q0, q1;
            q0.x = r0[y0]; q0.y = r0[y1]; q0.z = r0[y2]; q0.w = r0[y3];
            q1.x = r1[y0]; q1.y = r1[y1]; q1.z = r1[y2]; q1.w = r1[y3];
            *(f32x4*)(pk + ((uint32_t)x << 10) + woff) = q0;
            *(f32x4*)(pk + ((uint32_t)(x + 1) << 10) + woff) = q1;
        }
        const float INF = __builtin_inff();
        f32x4 qi; qi.x = INF; qi.y = INF; qi.z = INF; qi.w = INF;
        *(f32x4*)(pk + ((uint32_t)INF_ROW << 10) + woff) = qi;
    }
    __syncthreads();

    const int xl = xlen[b] - 1;            // rows 1..xl (>=1)
    const int yl = ylen[b] - 1;            // answer column (>=1)
    const int lane_ans = (yl - 1) >> 2;
    const int tstar = ((xl + 3) >> 2) + lane_ans;  // phase where lane_ans covers row xl
    const int r_star = (xl + 3) & 3;               // row index within that phase
    const int N = tstar - 1;                       // full phases before the tail

    const uint32_t lane16b = base32 + (uint32_t)(lane << 4);
    // sX quad address for phase p: base32 + SX_OFF + 1024 + 16(p-1) - 16*lane
    const uint32_t xa1 = base32 + SX_OFF + 1024u - (uint32_t)(lane << 4);

    // ---- prologue: x-quads for phases 1..3, then cost quads for phase 1 ----
    i32x4 xq1 = ds_load4i(xa1);          // x for phase 1
    i32x4 xgA = ds_load4i(xa1 + 16u);    // x for phase 2 (used by phase 1)
    i32x4 xgB = ds_load4i(xa1 + 32u);    // x for phase 3 (used by phase 2)
    WAITK(0);
    f32x4 qA0, qA1, qA2, qA3, qB0, qB1, qB2, qB3;
    qA0 = ds_load4((uint32_t)xq1.x + lane16b);
    qA1 = ds_load4((uint32_t)xq1.y + lane16b);
    qA2 = ds_load4((uint32_t)xq1.z + lane16b);
    qA3 = ds_load4((uint32_t)xq1.w + lane16b);
    uint32_t xaddr = xa1 + 48u;          // next sX quad: phase 4

    float g0 = 0.f, g1 = 0.f, g2 = 0.f, g3 = 0.f;
    float h0 = 0.f, h1 = 0.f, h2 = 0.f, h3 = 0.f;

    // ---- main loop: N phases, buffers alternate A,B,A,... ----
    int pairs = N >> 1;
    if (N & 1) {
        PHASE_FULL(A, B);
        for (; pairs > 0; --pairs) { PHASE_FULL(B, A); PHASE_FULL(A, B); }
        TAIL(B);
    } else {
        for (; pairs > 0; --pairs) { PHASE_FULL(A, B); PHASE_FULL(B, A); }
        TAIL(A);
    }

    // ---- answer: D[xl][yl] = g + xl + yl ----
    if (lane == lane_ans) {
        int slot = (yl - 1) & 3;
        float r = (slot == 0) ? g0 : (slot == 1) ? g1 : (slot == 2) ? g2 : g3;
        out[b] = r + (float)(xl + yl);
    }
}

extern "C" void kernel_launch(void* const* d_in, const int* in_sizes, int n_in,
                              void* d_out, int out_size, void* d_ws, size_t ws_size,
                              hipStream_t stream) {
    const float* P  = (const float*)d_in[0];
    const int* xs   = (const int*)d_in[1];
    const int* ys   = (const int*)d_in[2];
    const int* xlen = (const int*)d_in[3];
    const int* ylen = (const int*)d_in[4];
    float* out = (float*)d_out;
    float* C = (float*)d_ws;  // S_DIM*A_DIM floats, holds -1 - softmax(P)

    (void)hipFuncSetAttribute((const void*)dp_kernel,
                              hipFuncAttributeMaxDynamicSharedMemorySize, LDS_BYTES);

    softmax_kernel<<<S_DIM, 64, 0, stream>>>(P, C);
    dp_kernel<<<B_DIM, 64, LDS_BYTES, stream>>>(C, xs, ys, xlen, ylen, out);
}